// Round 6
// baseline (515.368 us; speedup 1.0000x reference)
//
#include <hip/hip_runtime.h>

#define N_NODES 50000
#define N_EDGES 800000
#define N_GRAPHS 500
#define DH 128
#define OUT_STRIDE 384
#define BN_EPS 1e-5f
#define SCAN_NB ((N_NODES + 255) / 256)

typedef __attribute__((ext_vector_type(8))) short bf16x8;
typedef __attribute__((ext_vector_type(4))) float f32x4;

__device__ __forceinline__ float4 ld4(const float* p) { return *(const float4*)p; }
__device__ __forceinline__ void st4(float* p, float4 v) { *(float4*)p = v; }
__device__ __forceinline__ void st4nt(float4* p, float4 v) {
    f32x4 nv = {v.x, v.y, v.z, v.w};
    __builtin_nontemporal_store(nv, (f32x4*)p);
}

__device__ __forceinline__ short f2bf(float f) {
    union { float f; unsigned u; } v; v.f = f;
    unsigned r = v.u + 0x7FFFu + ((v.u >> 16) & 1u);
    return (short)(r >> 16);
}
__device__ __forceinline__ float bu2f(unsigned short v) {
    union { unsigned u; float f; } x; x.u = ((unsigned)v) << 16; return x.f;
}

// ---------------- CSR build ----------------
__global__ void count_deg_k(const int* __restrict__ dst, int* __restrict__ deg, int E) {
    int q = E >> 2;
    int t = blockIdx.x * 256 + threadIdx.x;
    if (t >= q) return;
    int d0 = dst[t], d1 = dst[t + q], d2 = dst[t + 2 * q], d3 = dst[t + 3 * q];
    atomicAdd(&deg[d0], 1);
    atomicAdd(&deg[d1], 1);
    atomicAdd(&deg[d2], 1);
    atomicAdd(&deg[d3], 1);
}

// hierarchical scan: block sums -> scan sums -> block-local scan + offset
__global__ void deg_bsum_k(const int* __restrict__ deg, int* __restrict__ bsum, int n) {
    __shared__ int red[256];
    int t = threadIdx.x, i = blockIdx.x * 256 + t;
    red[t] = (i < n) ? deg[i] : 0;
    __syncthreads();
    for (int off = 128; off > 0; off >>= 1) {
        if (t < off) red[t] += red[t + off];
        __syncthreads();
    }
    if (t == 0) bsum[blockIdx.x] = red[0];
}

__global__ void bsum_scan_k(const int* __restrict__ bsum, int* __restrict__ boff,
                            int* __restrict__ rowstart, int nb, int n) {
    __shared__ int s[256];
    int t = threadIdx.x;
    int v = (t < nb) ? bsum[t] : 0;
    s[t] = v;
    __syncthreads();
    for (int off = 1; off < 256; off <<= 1) {
        int u = (t >= off) ? s[t - off] : 0;
        __syncthreads();
        s[t] += u;
        __syncthreads();
    }
    if (t < nb) boff[t] = s[t] - v;
    if (t == 255) rowstart[n] = s[255];
}

__global__ void deg_scan_k(const int* __restrict__ deg, const int* __restrict__ boff,
                           int* __restrict__ rowstart, int* __restrict__ cursor, int n) {
    __shared__ int s[256];
    int t = threadIdx.x, i = blockIdx.x * 256 + t;
    int v = (i < n) ? deg[i] : 0;
    s[t] = v;
    __syncthreads();
    for (int off = 1; off < 256; off <<= 1) {
        int u = (t >= off) ? s[t - off] : 0;
        __syncthreads();
        s[t] += u;
        __syncthreads();
    }
    if (i < n) {
        int r = boff[blockIdx.x] + s[t] - v;
        rowstart[i] = r;
        cursor[i] = r;
    }
}

// interleaved adjacency payload: {src(int bits), e0, e1, e2}; 4 edges/thread for ILP
__global__ void csr_fill_k(const int* __restrict__ src, const int* __restrict__ dst,
                           const float* __restrict__ ea, int* __restrict__ cursor,
                           float4* __restrict__ adj, int E) {
    int q = E >> 2;
    int t = blockIdx.x * 256 + threadIdx.x;
    if (t >= q) return;
    int e0 = t, e1 = t + q, e2 = t + 2 * q, e3 = t + 3 * q;
    int d0 = dst[e0], d1 = dst[e1], d2 = dst[e2], d3 = dst[e3];
    int s0 = src[e0], s1 = src[e1], s2 = src[e2], s3 = src[e3];
    float a00 = ea[e0 * 3], a01 = ea[e0 * 3 + 1], a02 = ea[e0 * 3 + 2];
    float a10 = ea[e1 * 3], a11 = ea[e1 * 3 + 1], a12 = ea[e1 * 3 + 2];
    float a20 = ea[e2 * 3], a21 = ea[e2 * 3 + 1], a22 = ea[e2 * 3 + 2];
    float a30 = ea[e3 * 3], a31 = ea[e3 * 3 + 1], a32 = ea[e3 * 3 + 2];
    int p0 = atomicAdd(&cursor[d0], 1);
    int p1 = atomicAdd(&cursor[d1], 1);
    int p2 = atomicAdd(&cursor[d2], 1);
    int p3 = atomicAdd(&cursor[d3], 1);
    st4nt(&adj[p0], make_float4(__int_as_float(s0), a00, a01, a02));
    st4nt(&adj[p1], make_float4(__int_as_float(s1), a10, a11, a12));
    st4nt(&adj[p2], make_float4(__int_as_float(s2), a20, a21, a22));
    st4nt(&adj[p3], make_float4(__int_as_float(s3), a30, a31, a32));
}

// ---------------- graph boundaries (batch is sorted) ----------------
__global__ void graph_bounds_k(const int* __restrict__ batch, int* __restrict__ gstart, int n, int G) {
    int i = blockIdx.x * 256 + threadIdx.x;
    if (i >= n) return;
    int b = batch[i];
    if (i == 0) {
        for (int g = 0; g <= b; ++g) gstart[g] = 0;
    } else {
        int p = batch[i - 1];
        for (int g = p + 1; g <= b; ++g) gstart[g] = i;
    }
    if (i == n - 1) {
        for (int g = b + 1; g <= G; ++g) gstart[g] = n;
    }
}

// ---------------- prep: pad x to stride 12; We transposes; W -> MFMA B-frags ----------------
__global__ void pad_x_k(const float* __restrict__ x, float* __restrict__ x12, int n) {
    int i = blockIdx.x * 256 + threadIdx.x;
    if (i >= n) return;
    const float* s = x + (size_t)i * 9;
    float* d = x12 + (size_t)i * 12;
    st4(d, make_float4(s[0], s[1], s[2], s[3]));
    st4(d + 4, make_float4(s[4], s[5], s[6], s[7]));
    st4(d + 8, make_float4(s[8], 0.f, 0.f, 0.f));
}

__global__ void transposeWe_k(const float* __restrict__ A, const float* __restrict__ B,
                              float* __restrict__ TA, float* __restrict__ TB) {
    const float* in = blockIdx.y ? B : A;
    float* out = blockIdx.y ? TB : TA;
    int idx = blockIdx.x * 256 + threadIdx.x;
    if (idx < 384) {
        int r = idx / 3, c = idx - r * 3;
        out[c * 128 + r] = in[idx];
    }
}

struct WfragArgs {
    const float* W[6];
    short* WF[6];
    int din[6];
    int KP[6];
};

// chunkIdx = (nt*NC + c)*16 + n16, n = nt*16+n16, k = c*8+j, NC = KP/8
__global__ void wfrag_all_k(WfragArgs a) {
    int which = blockIdx.y;
    int din = a.din[which], KP = a.KP[which];
    const float* W = a.W[which];
    short* WF = a.WF[which];
    int NC = KP >> 3;
    int total = 8 * NC * 16;
    int idx = blockIdx.x * 256 + threadIdx.x;
    if (idx >= total) return;
    int n16 = idx & 15;
    int rest = idx >> 4;
    int c = rest % NC;
    int nt = rest / NC;
    int n = nt * 16 + n16;
    union { short s[8]; int4 v; } u;
#pragma unroll
    for (int j = 0; j < 8; ++j) {
        int k = c * 8 + j;
        float val = (k < din) ? W[(size_t)n * din + k] : 0.f;
        u.s[j] = f2bf(val);
    }
    ((int4*)WF)[idx] = u.v;
}

// ---------------- aggregation layer 0: y[n][32] = pad(x + sum relu(x[src]+Lin(ea))) ----------------
__global__ __launch_bounds__(256) void agg_d9_k(
    const float* __restrict__ x12, const int* __restrict__ rowstart,
    const float4* __restrict__ adj,
    const float* __restrict__ We /*[9][3]*/, const float* __restrict__ be,
    float* __restrict__ y /*[n][32]*/, int n) {
    int i = blockIdx.x * 256 + threadIdx.x;
    if (i >= n) return;
    float w0[9], w1[9], w2[9], bb[9], acc[9];
#pragma unroll
    for (int j = 0; j < 9; ++j) {
        w0[j] = We[j * 3 + 0];
        w1[j] = We[j * 3 + 1];
        w2[j] = We[j * 3 + 2];
        bb[j] = be[j];
    }
    {
        const float* xr = x12 + (size_t)i * 12;
#pragma unroll
        for (int j = 0; j < 9; ++j) acc[j] = xr[j];
    }
    int k1 = rowstart[i + 1];
    for (int k = rowstart[i]; k < k1; ++k) {
        float4 ed = adj[k];
        int s = __float_as_int(ed.x);
        float e0 = ed.y, e1 = ed.z, e2 = ed.w;
        const float* xr = x12 + (size_t)s * 12;
        float4 r0 = ld4(xr), r1 = ld4(xr + 4), r2 = ld4(xr + 8);
        float xv[9] = {r0.x, r0.y, r0.z, r0.w, r1.x, r1.y, r1.z, r1.w, r2.x};
#pragma unroll
        for (int j = 0; j < 9; ++j) {
            float lin = fmaf(w0[j], e0, fmaf(w1[j], e1, fmaf(w2[j], e2, bb[j])));
            acc[j] += fmaxf(xv[j] + lin, 0.f);
        }
    }
    float* yp = y + (size_t)i * 32;
#pragma unroll
    for (int j = 0; j < 9; ++j) yp[j] = acc[j];
#pragma unroll
    for (int j = 9; j < 32; ++j) yp[j] = 0.f;
}

// ---------------- aggregation d=128: one wave per node, edge-halves, 2x unroll ----------------
__global__ __launch_bounds__(256) void agg_d128_k(
    const float* __restrict__ h, const unsigned short* __restrict__ hbf,
    const int* __restrict__ rowstart, const float4* __restrict__ adj,
    const float* __restrict__ WeT /*[3][128]*/, const float* __restrict__ be,
    float* __restrict__ y, int n) {
    int lane = threadIdx.x & 63;
    int node = blockIdx.x * 4 + (threadIdx.x >> 6);
    if (node >= n) return;
    int l31 = lane & 31, half = lane >> 5;
    int c = l31 * 4;
    float4 w0 = ld4(&WeT[0 * 128 + c]);
    float4 w1 = ld4(&WeT[1 * 128 + c]);
    float4 w2 = ld4(&WeT[2 * 128 + c]);
    float4 b4 = ld4(&be[c]);
    float4 acc = make_float4(0.f, 0.f, 0.f, 0.f);
    const ushort4* hb = (const ushort4*)hbf;
    int k1 = rowstart[node + 1];
    int k = rowstart[node] + half;
    for (; k + 2 < k1; k += 4) {
        float4 eda = adj[k], edb = adj[k + 2];
        int s0 = __float_as_int(eda.x), s1 = __float_as_int(edb.x);
        ushort4 ua = hb[(size_t)s0 * 32 + l31];
        ushort4 ub = hb[(size_t)s1 * 32 + l31];
        float ax = fmaf(w0.x, eda.y, fmaf(w1.x, eda.z, fmaf(w2.x, eda.w, b4.x))) + bu2f(ua.x);
        float ay = fmaf(w0.y, eda.y, fmaf(w1.y, eda.z, fmaf(w2.y, eda.w, b4.y))) + bu2f(ua.y);
        float az = fmaf(w0.z, eda.y, fmaf(w1.z, eda.z, fmaf(w2.z, eda.w, b4.z))) + bu2f(ua.z);
        float aw = fmaf(w0.w, eda.y, fmaf(w1.w, eda.z, fmaf(w2.w, eda.w, b4.w))) + bu2f(ua.w);
        float bx = fmaf(w0.x, edb.y, fmaf(w1.x, edb.z, fmaf(w2.x, edb.w, b4.x))) + bu2f(ub.x);
        float by = fmaf(w0.y, edb.y, fmaf(w1.y, edb.z, fmaf(w2.y, edb.w, b4.y))) + bu2f(ub.y);
        float bz = fmaf(w0.z, edb.y, fmaf(w1.z, edb.z, fmaf(w2.z, edb.w, b4.z))) + bu2f(ub.z);
        float bw = fmaf(w0.w, edb.y, fmaf(w1.w, edb.z, fmaf(w2.w, edb.w, b4.w))) + bu2f(ub.w);
        acc.x += fmaxf(ax, 0.f) + fmaxf(bx, 0.f);
        acc.y += fmaxf(ay, 0.f) + fmaxf(by, 0.f);
        acc.z += fmaxf(az, 0.f) + fmaxf(bz, 0.f);
        acc.w += fmaxf(aw, 0.f) + fmaxf(bw, 0.f);
    }
    if (k < k1) {
        float4 ed = adj[k];
        int s = __float_as_int(ed.x);
        ushort4 ua = hb[(size_t)s * 32 + l31];
        float mx = fmaf(w0.x, ed.y, fmaf(w1.x, ed.z, fmaf(w2.x, ed.w, b4.x))) + bu2f(ua.x);
        float my = fmaf(w0.y, ed.y, fmaf(w1.y, ed.z, fmaf(w2.y, ed.w, b4.y))) + bu2f(ua.y);
        float mz = fmaf(w0.z, ed.y, fmaf(w1.z, ed.z, fmaf(w2.z, ed.w, b4.z))) + bu2f(ua.z);
        float mw = fmaf(w0.w, ed.y, fmaf(w1.w, ed.z, fmaf(w2.w, ed.w, b4.w))) + bu2f(ua.w);
        acc.x += fmaxf(mx, 0.f);
        acc.y += fmaxf(my, 0.f);
        acc.z += fmaxf(mz, 0.f);
        acc.w += fmaxf(mw, 0.f);
    }
    acc.x += __shfl_xor(acc.x, 32);
    acc.y += __shfl_xor(acc.y, 32);
    acc.z += __shfl_xor(acc.z, 32);
    acc.w += __shfl_xor(acc.w, 32);
    if (half == 0) {
        float4 xv = ld4(&h[(size_t)node * 128 + c]);
        acc.x += xv.x;
        acc.y += xv.y;
        acc.z += xv.z;
        acc.w += xv.w;
        st4(&y[(size_t)node * 128 + c], acc);
    }
}

// ---------------- A-fragment helpers ----------------
__device__ __forceinline__ bf16x8 loadA(const float* p, bool v) {
    union { short s[8]; bf16x8 v8; } u;
    if (v) {
        float4 a = ld4(p), b = ld4(p + 4);
        u.s[0] = f2bf(a.x); u.s[1] = f2bf(a.y); u.s[2] = f2bf(a.z); u.s[3] = f2bf(a.w);
        u.s[4] = f2bf(b.x); u.s[5] = f2bf(b.y); u.s[6] = f2bf(b.z); u.s[7] = f2bf(b.w);
    } else {
#pragma unroll
        for (int j = 0; j < 8; ++j) u.s[j] = 0;
    }
    return u.v8;
}

__device__ __forceinline__ bf16x8 loadA_bn(const float* p, bool v,
                                           float4 sc0, float4 sc1, float4 sh0, float4 sh1) {
    union { short s[8]; bf16x8 v8; } u;
    if (v) {
        float4 a = ld4(p), b = ld4(p + 4);
        u.s[0] = f2bf(fmaxf(fmaf(a.x, sc0.x, sh0.x), 0.f));
        u.s[1] = f2bf(fmaxf(fmaf(a.y, sc0.y, sh0.y), 0.f));
        u.s[2] = f2bf(fmaxf(fmaf(a.z, sc0.z, sh0.z), 0.f));
        u.s[3] = f2bf(fmaxf(fmaf(a.w, sc0.w, sh0.w), 0.f));
        u.s[4] = f2bf(fmaxf(fmaf(b.x, sc1.x, sh1.x), 0.f));
        u.s[5] = f2bf(fmaxf(fmaf(b.y, sc1.y, sh1.y), 0.f));
        u.s[6] = f2bf(fmaxf(fmaf(b.z, sc1.z, sh1.z), 0.f));
        u.s[7] = f2bf(fmaxf(fmaf(b.w, sc1.w, sh1.w), 0.f));
    } else {
#pragma unroll
        for (int j = 0; j < 8; ++j) u.s[j] = 0;
    }
    return u.v8;
}

// ---------------- MFMA GEMM1: H = Y @ Wt, + BN column stats ----------------
template <int KP>
__global__ __launch_bounds__(256) void mgemm1_k(
    const float* Y /* [n][KP] */, const short* __restrict__ WF,
    float* Hout /* [n][128] */, float* __restrict__ col_sum, float* __restrict__ col_sumsq, int n) {
    constexpr int NC = KP / 8;
    constexpr int KB = KP / 32;
    __shared__ short Wlds[8 * NC * 16 * 8];
    __shared__ float red[256];
    const int t = threadIdx.x;
    const int lane = t & 63, w = t >> 6;
    const int l15 = lane & 15, q = lane >> 4;
    const int row0 = blockIdx.x * 128 + w * 32;

    {
        const int4* s = (const int4*)WF;
        int4* d = (int4*)Wlds;
        for (int i = t; i < 8 * NC * 16; i += 256) d[i] = s[i];
    }
    red[t] = 0.f;
    __syncthreads();

    f32x4 acc[2][8];
#pragma unroll
    for (int rt = 0; rt < 2; ++rt)
#pragma unroll
        for (int nt = 0; nt < 8; ++nt) acc[rt][nt] = (f32x4){0.f, 0.f, 0.f, 0.f};

    const int r0 = row0 + l15, r1 = row0 + 16 + l15;
    const float* p0 = Y + (size_t)r0 * KP + q * 8;
    const float* p1 = Y + (size_t)r1 * KP + q * 8;
    const bool v0 = r0 < n, v1 = r1 < n;
    const bf16x8* WL = (const bf16x8*)Wlds;

#pragma unroll
    for (int b = 0; b < KB; ++b) {
        bf16x8 a0 = loadA(p0 + b * 32, v0);
        bf16x8 a1 = loadA(p1 + b * 32, v1);
#pragma unroll
        for (int nt = 0; nt < 8; ++nt) {
            bf16x8 bf = WL[(nt * NC + b * 4 + q) * 16 + l15];
            acc[0][nt] = __builtin_amdgcn_mfma_f32_16x16x32_bf16(a0, bf, acc[0][nt], 0, 0, 0);
            acc[1][nt] = __builtin_amdgcn_mfma_f32_16x16x32_bf16(a1, bf, acc[1][nt], 0, 0, 0);
        }
    }

#pragma unroll
    for (int nt = 0; nt < 8; ++nt) {
        float s = 0.f, ss = 0.f;
#pragma unroll
        for (int rt = 0; rt < 2; ++rt) {
            int rb = row0 + rt * 16 + q * 4;
#pragma unroll
            for (int i = 0; i < 4; ++i) {
                float d = acc[rt][nt][i];
                int r = rb + i;
                if (r < n) Hout[(size_t)r * 128 + nt * 16 + l15] = d;
                s += d;
                ss += d * d;
            }
        }
        s += __shfl_xor(s, 16);
        s += __shfl_xor(s, 32);
        ss += __shfl_xor(ss, 16);
        ss += __shfl_xor(ss, 32);
        if (lane < 16) {
            atomicAdd(&red[nt * 16 + l15], s);
            atomicAdd(&red[128 + nt * 16 + l15], ss);
        }
    }
    __syncthreads();
    if (t < 128) atomicAdd(&col_sum[t], red[t]);
    else atomicAdd(&col_sumsq[t - 128], red[t]);
}

// ---------------- BN finalize: scale/shift ----------------
__global__ void bn_finalize_k(const float* __restrict__ col_sum, const float* __restrict__ col_sumsq,
                              const float* __restrict__ g, const float* __restrict__ b,
                              float* __restrict__ scale, float* __restrict__ shift, int n) {
    int j = threadIdx.x;
    float inv_n = 1.0f / (float)n;
    float mean = col_sum[j] * inv_n;
    float var = col_sumsq[j] * inv_n - mean * mean;
    float a = g[j] * rsqrtf(var + BN_EPS);
    scale[j] = a;
    shift[j] = fmaf(-mean, a, b[j]);
}

// ---------------- MFMA GEMM2: h = relu(relu(BN(Hpre)) @ Wt + b2); fp32 (+opt bf16) stores ----------------
__global__ __launch_bounds__(256) void mgemm2_k(
    const float* Hpre, const short* __restrict__ WF,
    const float* __restrict__ scale, const float* __restrict__ shift,
    const float* __restrict__ bias, float* Hout, unsigned short* __restrict__ Hbf, int n) {
    constexpr int NC = 16;
    __shared__ short Wlds[8 * NC * 16 * 8];
    const int t = threadIdx.x;
    const int lane = t & 63, w = t >> 6;
    const int l15 = lane & 15, q = lane >> 4;
    const int row0 = blockIdx.x * 128 + w * 32;

    {
        const int4* s = (const int4*)WF;
        int4* d = (int4*)Wlds;
        for (int i = t; i < 8 * NC * 16; i += 256) d[i] = s[i];
    }
    __syncthreads();

    f32x4 acc[2][8];
#pragma unroll
    for (int rt = 0; rt < 2; ++rt)
#pragma unroll
        for (int nt = 0; nt < 8; ++nt) acc[rt][nt] = (f32x4){0.f, 0.f, 0.f, 0.f};

    const int r0 = row0 + l15, r1 = row0 + 16 + l15;
    const float* p0 = Hpre + (size_t)r0 * 128 + q * 8;
    const float* p1 = Hpre + (size_t)r1 * 128 + q * 8;
    const bool v0 = r0 < n, v1 = r1 < n;
    const bf16x8* WL = (const bf16x8*)Wlds;

#pragma unroll
    for (int b = 0; b < 4; ++b) {
        const int k0 = b * 32 + q * 8;
        float4 sc0 = ld4(&scale[k0]), sc1 = ld4(&scale[k0 + 4]);
        float4 sh0 = ld4(&shift[k0]), sh1 = ld4(&shift[k0 + 4]);
        bf16x8 a0 = loadA_bn(p0 + b * 32, v0, sc0, sc1, sh0, sh1);
        bf16x8 a1 = loadA_bn(p1 + b * 32, v1, sc0, sc1, sh0, sh1);
#pragma unroll
        for (int nt = 0; nt < 8; ++nt) {
            bf16x8 bf = WL[(nt * NC + b * 4 + q) * 16 + l15];
            acc[0][nt] = __builtin_amdgcn_mfma_f32_16x16x32_bf16(a0, bf, acc[0][nt], 0, 0, 0);
            acc[1][nt] = __builtin_amdgcn_mfma_f32_16x16x32_bf16(a1, bf, acc[1][nt], 0, 0, 0);
        }
    }

#pragma unroll
    for (int nt = 0; nt < 8; ++nt) {
        float bcol = bias[nt * 16 + l15];
#pragma unroll
        for (int rt = 0; rt < 2; ++rt) {
            int rb = row0 + rt * 16 + q * 4;
#pragma unroll
            for (int i = 0; i < 4; ++i) {
                int r = rb + i;
                if (r < n) {
                    float o = fmaxf(acc[rt][nt][i] + bcol, 0.f);
                    Hout[(size_t)r * 128 + nt * 16 + l15] = o;
                    if (Hbf) Hbf[(size_t)r * 128 + nt * 16 + l15] = (unsigned short)f2bf(o);
                }
            }
        }
    }
}

// ---------------- per-graph pool (exclusive ranges, no atomics) ----------------
__global__ __launch_bounds__(256) void pool_k(
    const float* __restrict__ H, const int* __restrict__ gstart,
    float* __restrict__ out /* base + layer*128 */) {
    int g = blockIdx.x;
    int t = threadIdx.x;
    int c = t & 127;
    int half = t >> 7;  // 0/1
    int r0 = gstart[g], r1 = gstart[g + 1];
    float s = 0.f;
    for (int r = r0 + half; r < r1; r += 2) s += H[(size_t)r * 128 + c];
    __shared__ float red[256];
    red[t] = s;
    __syncthreads();
    if (t < 128) out[(size_t)g * OUT_STRIDE + t] = red[t] + red[t + 128];
}

extern "C" void kernel_launch(void* const* d_in, const int* in_sizes, int n_in,
                              void* d_out, int out_size, void* d_ws, size_t ws_size,
                              hipStream_t stream) {
    const float* x = (const float*)d_in[0];
    const int* ei = (const int*)d_in[1];
    const float* ea = (const float*)d_in[2];
    const int* batch = (const int*)d_in[3];
    const int* srcArr = ei;
    const int* dstArr = ei + N_EDGES;

    const float *We[3], *be[3], *W1[3], *gP[3], *bP[3], *W2[3], *b2[3];
    for (int l = 0; l < 3; ++l) {
        int base = 4 + 7 * l;
        We[l] = (const float*)d_in[base + 0];
        be[l] = (const float*)d_in[base + 1];
        W1[l] = (const float*)d_in[base + 2];
        gP[l] = (const float*)d_in[base + 3];
        bP[l] = (const float*)d_in[base + 4];
        W2[l] = (const float*)d_in[base + 5];
        b2[l] = (const float*)d_in[base + 6];
    }

    char* w = (char*)d_ws;
    auto carve = [&](size_t bytes) {
        char* p = w;
        w += (bytes + 255) & ~(size_t)255;
        return p;
    };
    int* deg = (int*)carve((size_t)N_NODES * 4);
    int* rowstart = (int*)carve((size_t)(N_NODES + 1) * 4);
    int* cursor = (int*)carve((size_t)N_NODES * 4);
    int* bsum = (int*)carve((size_t)SCAN_NB * 4);
    int* boff = (int*)carve((size_t)SCAN_NB * 4);
    int* gstart = (int*)carve((size_t)(N_GRAPHS + 1) * 4);
    float4* adj = (float4*)carve((size_t)N_EDGES * 16);
    float* WeT1 = (float*)carve(3 * 128 * 4);
    float* WeT2 = (float*)carve(3 * 128 * 4);
    short* WF1_0 = (short*)carve(8 * 4 * 16 * 8 * 2);    // KP=32
    short* WF1_1 = (short*)carve(8 * 16 * 16 * 8 * 2);   // KP=128
    short* WF1_2 = (short*)carve(8 * 16 * 16 * 8 * 2);
    short* WF2_0 = (short*)carve(8 * 16 * 16 * 8 * 2);
    short* WF2_1 = (short*)carve(8 * 16 * 16 * 8 * 2);
    short* WF2_2 = (short*)carve(8 * 16 * 16 * 8 * 2);
    float* stats = (float*)carve(3 * 256 * 4);           // per-layer col_sum/col_sumsq
    float* scsh = (float*)carve(2 * 128 * 4);            // scale/shift (reused per layer)
    float* x12 = (float*)carve((size_t)N_NODES * 12 * 4);
    float* y0p = (float*)carve((size_t)N_NODES * 32 * 4);
    float* hA = (float*)carve((size_t)N_NODES * 128 * 4);
    float* ybuf = (float*)carve((size_t)N_NODES * 128 * 4);
    unsigned short* hbf = (unsigned short*)carve((size_t)N_NODES * 128 * 2);
    float* scale = scsh;
    float* shift = scsh + 128;

    hipMemsetAsync(deg, 0, (size_t)N_NODES * 4, stream);
    hipMemsetAsync(stats, 0, 3 * 256 * 4, stream);

    count_deg_k<<<(N_EDGES / 4 + 255) / 256, 256, 0, stream>>>(dstArr, deg, N_EDGES);
    deg_bsum_k<<<SCAN_NB, 256, 0, stream>>>(deg, bsum, N_NODES);
    bsum_scan_k<<<1, 256, 0, stream>>>(bsum, boff, rowstart, SCAN_NB, N_NODES);
    deg_scan_k<<<SCAN_NB, 256, 0, stream>>>(deg, boff, rowstart, cursor, N_NODES);
    csr_fill_k<<<(N_EDGES / 4 + 255) / 256, 256, 0, stream>>>(srcArr, dstArr, ea, cursor, adj, N_EDGES);
    graph_bounds_k<<<(N_NODES + 255) / 256, 256, 0, stream>>>(batch, gstart, N_NODES, N_GRAPHS);
    pad_x_k<<<(N_NODES + 255) / 256, 256, 0, stream>>>(x, x12, N_NODES);

    {
        dim3 g2(2, 2);
        transposeWe_k<<<g2, 256, 0, stream>>>(We[1], We[2], WeT1, WeT2);
        WfragArgs wa;
        wa.W[0] = W1[0]; wa.WF[0] = WF1_0; wa.din[0] = 9;   wa.KP[0] = 32;
        wa.W[1] = W1[1]; wa.WF[1] = WF1_1; wa.din[1] = 128; wa.KP[1] = 128;
        wa.W[2] = W1[2]; wa.WF[2] = WF1_2; wa.din[2] = 128; wa.KP[2] = 128;
        wa.W[3] = W2[0]; wa.WF[3] = WF2_0; wa.din[3] = 128; wa.KP[3] = 128;
        wa.W[4] = W2[1]; wa.WF[4] = WF2_1; wa.din[4] = 128; wa.KP[4] = 128;
        wa.W[5] = W2[2]; wa.WF[5] = WF2_2; wa.din[5] = 128; wa.KP[5] = 128;
        dim3 gw(8, 6);
        wfrag_all_k<<<gw, 256, 0, stream>>>(wa);
    }

    const int gM = (N_NODES + 127) / 128;
    const int gAgg = (N_NODES + 3) / 4;
    float* out_f = (float*)d_out;

    // ---- layer 0 (K=32 padded from din=9) ----
    agg_d9_k<<<(N_NODES + 255) / 256, 256, 0, stream>>>(x12, rowstart, adj, We[0], be[0], y0p, N_NODES);
    mgemm1_k<32><<<gM, 256, 0, stream>>>(y0p, WF1_0, hA, stats, stats + 128, N_NODES);
    bn_finalize_k<<<1, 128, 0, stream>>>(stats, stats + 128, gP[0], bP[0], scale, shift, N_NODES);
    mgemm2_k<<<gM, 256, 0, stream>>>(hA, WF2_0, scale, shift, b2[0], hA, hbf, N_NODES);
    pool_k<<<N_GRAPHS, 256, 0, stream>>>(hA, gstart, out_f + 0);

    // ---- layer 1 ----
    agg_d128_k<<<gAgg, 256, 0, stream>>>(hA, hbf, rowstart, adj, WeT1, be[1], ybuf, N_NODES);
    mgemm1_k<128><<<gM, 256, 0, stream>>>(ybuf, WF1_1, ybuf, stats + 256, stats + 384, N_NODES);
    bn_finalize_k<<<1, 128, 0, stream>>>(stats + 256, stats + 384, gP[1], bP[1], scale, shift, N_NODES);
    mgemm2_k<<<gM, 256, 0, stream>>>(ybuf, WF2_1, scale, shift, b2[1], ybuf, hbf, N_NODES);
    pool_k<<<N_GRAPHS, 256, 0, stream>>>(ybuf, gstart, out_f + 128);

    // ---- layer 2 ----
    agg_d128_k<<<gAgg, 256, 0, stream>>>(ybuf, hbf, rowstart, adj, WeT2, be[2], hA, N_NODES);
    mgemm1_k<128><<<gM, 256, 0, stream>>>(hA, WF1_2, hA, stats + 512, stats + 640, N_NODES);
    bn_finalize_k<<<1, 128, 0, stream>>>(stats + 512, stats + 640, gP[2], bP[2], scale, shift, N_NODES);
    mgemm2_k<<<gM, 256, 0, stream>>>(hA, WF2_2, scale, shift, b2[2], hA, nullptr, N_NODES);
    pool_k<<<N_GRAPHS, 256, 0, stream>>>(hA, gstart, out_f + 256);
}

// Round 7
// 470.903 us; speedup vs baseline: 1.0944x; 1.0944x over previous
//
#include <hip/hip_runtime.h>

#define N_NODES 50000
#define N_EDGES 800000
#define N_GRAPHS 500
#define DH 128
#define OUT_STRIDE 384
#define BN_EPS 1e-5f
#define SCAN_NB ((N_NODES + 255) / 256)

typedef __attribute__((ext_vector_type(8))) short bf16x8;
typedef __attribute__((ext_vector_type(4))) float f32x4;

__device__ __forceinline__ float4 ld4(const float* p) { return *(const float4*)p; }
__device__ __forceinline__ void st4(float* p, float4 v) { *(float4*)p = v; }

__device__ __forceinline__ short f2bf(float f) {
    union { float f; unsigned u; } v; v.f = f;
    unsigned r = v.u + 0x7FFFu + ((v.u >> 16) & 1u);
    return (short)(r >> 16);
}
__device__ __forceinline__ float bu2f(unsigned short v) {
    union { unsigned u; float f; } x; x.u = ((unsigned)v) << 16; return x.f;
}

// ---------------- fused prep: deg count (edge) + pad_x + graph bounds (node) ----------------
__global__ void prep_k(const int* __restrict__ dst, int* __restrict__ deg,
                       const float* __restrict__ x, float* __restrict__ x12,
                       const int* __restrict__ batch, int* __restrict__ gstart,
                       int E, int n, int G) {
    int i = blockIdx.x * 256 + threadIdx.x;
    if (i < E) atomicAdd(&deg[dst[i]], 1);
    if (i < n) {
        const float* s = x + (size_t)i * 9;
        float* d = x12 + (size_t)i * 12;
        st4(d, make_float4(s[0], s[1], s[2], s[3]));
        st4(d + 4, make_float4(s[4], s[5], s[6], s[7]));
        st4(d + 8, make_float4(s[8], 0.f, 0.f, 0.f));
        int b = batch[i];
        if (i == 0) {
            for (int g = 0; g <= b; ++g) gstart[g] = 0;
        } else {
            int p = batch[i - 1];
            for (int g = p + 1; g <= b; ++g) gstart[g] = i;
        }
        if (i == n - 1) {
            for (int g = b + 1; g <= G; ++g) gstart[g] = n;
        }
    }
}

// hierarchical scan: block sums -> scan sums -> block-local scan + offset
__global__ void deg_bsum_k(const int* __restrict__ deg, int* __restrict__ bsum, int n) {
    __shared__ int red[256];
    int t = threadIdx.x, i = blockIdx.x * 256 + t;
    red[t] = (i < n) ? deg[i] : 0;
    __syncthreads();
    for (int off = 128; off > 0; off >>= 1) {
        if (t < off) red[t] += red[t + off];
        __syncthreads();
    }
    if (t == 0) bsum[blockIdx.x] = red[0];
}

__global__ void bsum_scan_k(const int* __restrict__ bsum, int* __restrict__ boff,
                            int* __restrict__ rowstart, int nb, int n) {
    __shared__ int s[256];
    int t = threadIdx.x;
    int v = (t < nb) ? bsum[t] : 0;
    s[t] = v;
    __syncthreads();
    for (int off = 1; off < 256; off <<= 1) {
        int u = (t >= off) ? s[t - off] : 0;
        __syncthreads();
        s[t] += u;
        __syncthreads();
    }
    if (t < nb) boff[t] = s[t] - v;
    if (t == 255) rowstart[n] = s[255];
}

__global__ void deg_scan_k(const int* __restrict__ deg, const int* __restrict__ boff,
                           int* __restrict__ rowstart, int* __restrict__ cursor, int n) {
    __shared__ int s[256];
    int t = threadIdx.x, i = blockIdx.x * 256 + t;
    int v = (i < n) ? deg[i] : 0;
    s[t] = v;
    __syncthreads();
    for (int off = 1; off < 256; off <<= 1) {
        int u = (t >= off) ? s[t - off] : 0;
        __syncthreads();
        s[t] += u;
        __syncthreads();
    }
    if (i < n) {
        int r = boff[blockIdx.x] + s[t] - v;
        rowstart[i] = r;
        cursor[i] = r;
    }
}

// interleaved adjacency payload {src(int bits), e0, e1, e2}; one edge/thread (max waves in flight)
__global__ void csr_fill_k(const int* __restrict__ src, const int* __restrict__ dst,
                           const float* __restrict__ ea, int* __restrict__ cursor,
                           float4* __restrict__ adj, int E) {
    int e = blockIdx.x * 256 + threadIdx.x;
    if (e >= E) return;
    int pos = atomicAdd(&cursor[dst[e]], 1);
    adj[pos] = make_float4(__int_as_float(src[e]), ea[e * 3 + 0], ea[e * 3 + 1], ea[e * 3 + 2]);
}

// ---------------- W -> bf16 MFMA B-frags (+ We transposes in slot y==6) ----------------
struct WfragArgs {
    const float* W[6];
    short* WF[6];
    int din[6];
    int KP[6];
    const float* We1;
    const float* We2;
    float* WeT1;
    float* WeT2;
};

__global__ void wfrag_all_k(WfragArgs a) {
    int which = blockIdx.y;
    int idx = blockIdx.x * 256 + threadIdx.x;
    if (which == 6) {
        if (idx < 384) {
            int r = idx / 3, c = idx - r * 3;
            a.WeT1[c * 128 + r] = a.We1[idx];
        } else if (idx < 768) {
            int j = idx - 384;
            int r = j / 3, c = j - r * 3;
            a.WeT2[c * 128 + r] = a.We2[j];
        }
        return;
    }
    int din = a.din[which], KP = a.KP[which];
    const float* W = a.W[which];
    short* WF = a.WF[which];
    int NC = KP >> 3;
    int total = 8 * NC * 16;
    if (idx >= total) return;
    int n16 = idx & 15;
    int rest = idx >> 4;
    int c = rest % NC;
    int nt = rest / NC;
    int n = nt * 16 + n16;
    union { short s[8]; int4 v; } u;
#pragma unroll
    for (int j = 0; j < 8; ++j) {
        int k = c * 8 + j;
        float val = (k < din) ? W[(size_t)n * din + k] : 0.f;
        u.s[j] = f2bf(val);
    }
    ((int4*)WF)[idx] = u.v;
}

// ---------------- aggregation layer 0: y[n][32] = pad(x + sum relu(x[src]+Lin(ea))) ----------------
__global__ __launch_bounds__(256) void agg_d9_k(
    const float* __restrict__ x12, const int* __restrict__ rowstart,
    const float4* __restrict__ adj,
    const float* __restrict__ We /*[9][3]*/, const float* __restrict__ be,
    float* __restrict__ y /*[n][32]*/, int n) {
    int i = blockIdx.x * 256 + threadIdx.x;
    if (i >= n) return;
    float w0[9], w1[9], w2[9], bb[9], acc[9];
#pragma unroll
    for (int j = 0; j < 9; ++j) {
        w0[j] = We[j * 3 + 0];
        w1[j] = We[j * 3 + 1];
        w2[j] = We[j * 3 + 2];
        bb[j] = be[j];
    }
    {
        const float* xr = x12 + (size_t)i * 12;
#pragma unroll
        for (int j = 0; j < 9; ++j) acc[j] = xr[j];
    }
    int k1 = rowstart[i + 1];
    for (int k = rowstart[i]; k < k1; ++k) {
        float4 ed = adj[k];
        int s = __float_as_int(ed.x);
        float e0 = ed.y, e1 = ed.z, e2 = ed.w;
        const float* xr = x12 + (size_t)s * 12;
        float4 r0 = ld4(xr), r1 = ld4(xr + 4), r2 = ld4(xr + 8);
        float xv[9] = {r0.x, r0.y, r0.z, r0.w, r1.x, r1.y, r1.z, r1.w, r2.x};
#pragma unroll
        for (int j = 0; j < 9; ++j) {
            float lin = fmaf(w0[j], e0, fmaf(w1[j], e1, fmaf(w2[j], e2, bb[j])));
            acc[j] += fmaxf(xv[j] + lin, 0.f);
        }
    }
    float* yp = y + (size_t)i * 32;
#pragma unroll
    for (int j = 0; j < 9; ++j) yp[j] = acc[j];
#pragma unroll
    for (int j = 9; j < 32; ++j) yp[j] = 0.f;
}

// ---------------- aggregation d=128: one wave/node, edge-halves, 4-deep gather ILP ----------------
__global__ __launch_bounds__(256) void agg_d128_k(
    const float* __restrict__ h, const unsigned short* __restrict__ hbf,
    const int* __restrict__ rowstart, const float4* __restrict__ adj,
    const float* __restrict__ WeT /*[3][128]*/, const float* __restrict__ be,
    float* __restrict__ y, int n) {
    int lane = threadIdx.x & 63;
    int node = blockIdx.x * 4 + (threadIdx.x >> 6);
    if (node >= n) return;
    int l31 = lane & 31, half = lane >> 5;
    int c = l31 * 4;
    float4 w0 = ld4(&WeT[0 * 128 + c]);
    float4 w1 = ld4(&WeT[1 * 128 + c]);
    float4 w2 = ld4(&WeT[2 * 128 + c]);
    float4 b4 = ld4(&be[c]);
    float4 acc = make_float4(0.f, 0.f, 0.f, 0.f);
    const ushort4* hb = (const ushort4*)hbf;
    int k1 = rowstart[node + 1];
    int k = rowstart[node] + half;
    for (; k + 6 < k1; k += 8) {
        float4 e[4] = {adj[k], adj[k + 2], adj[k + 4], adj[k + 6]};
        ushort4 u[4];
#pragma unroll
        for (int j = 0; j < 4; ++j) u[j] = hb[(size_t)__float_as_int(e[j].x) * 32 + l31];
#pragma unroll
        for (int j = 0; j < 4; ++j) {
            acc.x += fmaxf(fmaf(w0.x, e[j].y, fmaf(w1.x, e[j].z, fmaf(w2.x, e[j].w, b4.x))) + bu2f(u[j].x), 0.f);
            acc.y += fmaxf(fmaf(w0.y, e[j].y, fmaf(w1.y, e[j].z, fmaf(w2.y, e[j].w, b4.y))) + bu2f(u[j].y), 0.f);
            acc.z += fmaxf(fmaf(w0.z, e[j].y, fmaf(w1.z, e[j].z, fmaf(w2.z, e[j].w, b4.z))) + bu2f(u[j].z), 0.f);
            acc.w += fmaxf(fmaf(w0.w, e[j].y, fmaf(w1.w, e[j].z, fmaf(w2.w, e[j].w, b4.w))) + bu2f(u[j].w), 0.f);
        }
    }
    for (; k < k1; k += 2) {
        float4 ed = adj[k];
        int s = __float_as_int(ed.x);
        ushort4 ua = hb[(size_t)s * 32 + l31];
        acc.x += fmaxf(fmaf(w0.x, ed.y, fmaf(w1.x, ed.z, fmaf(w2.x, ed.w, b4.x))) + bu2f(ua.x), 0.f);
        acc.y += fmaxf(fmaf(w0.y, ed.y, fmaf(w1.y, ed.z, fmaf(w2.y, ed.w, b4.y))) + bu2f(ua.y), 0.f);
        acc.z += fmaxf(fmaf(w0.z, ed.y, fmaf(w1.z, ed.z, fmaf(w2.z, ed.w, b4.z))) + bu2f(ua.z), 0.f);
        acc.w += fmaxf(fmaf(w0.w, ed.y, fmaf(w1.w, ed.z, fmaf(w2.w, ed.w, b4.w))) + bu2f(ua.w), 0.f);
    }
    acc.x += __shfl_xor(acc.x, 32);
    acc.y += __shfl_xor(acc.y, 32);
    acc.z += __shfl_xor(acc.z, 32);
    acc.w += __shfl_xor(acc.w, 32);
    if (half == 0) {
        float4 xv = ld4(&h[(size_t)node * 128 + c]);
        acc.x += xv.x;
        acc.y += xv.y;
        acc.z += xv.z;
        acc.w += xv.w;
        st4(&y[(size_t)node * 128 + c], acc);
    }
}

// ---------------- A-fragment helpers ----------------
__device__ __forceinline__ bf16x8 loadA(const float* p, bool v) {
    union { short s[8]; bf16x8 v8; } u;
    if (v) {
        float4 a = ld4(p), b = ld4(p + 4);
        u.s[0] = f2bf(a.x); u.s[1] = f2bf(a.y); u.s[2] = f2bf(a.z); u.s[3] = f2bf(a.w);
        u.s[4] = f2bf(b.x); u.s[5] = f2bf(b.y); u.s[6] = f2bf(b.z); u.s[7] = f2bf(b.w);
    } else {
#pragma unroll
        for (int j = 0; j < 8; ++j) u.s[j] = 0;
    }
    return u.v8;
}

__device__ __forceinline__ bf16x8 loadA_bn(const float* p, bool v,
                                           float4 sc0, float4 sc1, float4 sh0, float4 sh1) {
    union { short s[8]; bf16x8 v8; } u;
    if (v) {
        float4 a = ld4(p), b = ld4(p + 4);
        u.s[0] = f2bf(fmaxf(fmaf(a.x, sc0.x, sh0.x), 0.f));
        u.s[1] = f2bf(fmaxf(fmaf(a.y, sc0.y, sh0.y), 0.f));
        u.s[2] = f2bf(fmaxf(fmaf(a.z, sc0.z, sh0.z), 0.f));
        u.s[3] = f2bf(fmaxf(fmaf(a.w, sc0.w, sh0.w), 0.f));
        u.s[4] = f2bf(fmaxf(fmaf(b.x, sc1.x, sh1.x), 0.f));
        u.s[5] = f2bf(fmaxf(fmaf(b.y, sc1.y, sh1.y), 0.f));
        u.s[6] = f2bf(fmaxf(fmaf(b.z, sc1.z, sh1.z), 0.f));
        u.s[7] = f2bf(fmaxf(fmaf(b.w, sc1.w, sh1.w), 0.f));
    } else {
#pragma unroll
        for (int j = 0; j < 8; ++j) u.s[j] = 0;
    }
    return u.v8;
}

// ---------------- MFMA GEMM1: H = Y @ Wt, + BN column stats ----------------
template <int KP>
__global__ __launch_bounds__(256) void mgemm1_k(
    const float* Y /* [n][KP] */, const short* __restrict__ WF,
    float* Hout /* [n][128] */, float* __restrict__ col_sum, float* __restrict__ col_sumsq, int n) {
    constexpr int NC = KP / 8;
    constexpr int KB = KP / 32;
    __shared__ short Wlds[8 * NC * 16 * 8];
    __shared__ float red[256];
    const int t = threadIdx.x;
    const int lane = t & 63, w = t >> 6;
    const int l15 = lane & 15, q = lane >> 4;
    const int row0 = blockIdx.x * 128 + w * 32;

    {
        const int4* s = (const int4*)WF;
        int4* d = (int4*)Wlds;
        for (int i = t; i < 8 * NC * 16; i += 256) d[i] = s[i];
    }
    red[t] = 0.f;
    __syncthreads();

    f32x4 acc[2][8];
#pragma unroll
    for (int rt = 0; rt < 2; ++rt)
#pragma unroll
        for (int nt = 0; nt < 8; ++nt) acc[rt][nt] = (f32x4){0.f, 0.f, 0.f, 0.f};

    const int r0 = row0 + l15, r1 = row0 + 16 + l15;
    const float* p0 = Y + (size_t)r0 * KP + q * 8;
    const float* p1 = Y + (size_t)r1 * KP + q * 8;
    const bool v0 = r0 < n, v1 = r1 < n;
    const bf16x8* WL = (const bf16x8*)Wlds;

#pragma unroll
    for (int b = 0; b < KB; ++b) {
        bf16x8 a0 = loadA(p0 + b * 32, v0);
        bf16x8 a1 = loadA(p1 + b * 32, v1);
#pragma unroll
        for (int nt = 0; nt < 8; ++nt) {
            bf16x8 bf = WL[(nt * NC + b * 4 + q) * 16 + l15];
            acc[0][nt] = __builtin_amdgcn_mfma_f32_16x16x32_bf16(a0, bf, acc[0][nt], 0, 0, 0);
            acc[1][nt] = __builtin_amdgcn_mfma_f32_16x16x32_bf16(a1, bf, acc[1][nt], 0, 0, 0);
        }
    }

#pragma unroll
    for (int nt = 0; nt < 8; ++nt) {
        float s = 0.f, ss = 0.f;
#pragma unroll
        for (int rt = 0; rt < 2; ++rt) {
            int rb = row0 + rt * 16 + q * 4;
#pragma unroll
            for (int i = 0; i < 4; ++i) {
                float d = acc[rt][nt][i];
                int r = rb + i;
                if (r < n) Hout[(size_t)r * 128 + nt * 16 + l15] = d;
                s += d;
                ss += d * d;
            }
        }
        s += __shfl_xor(s, 16);
        s += __shfl_xor(s, 32);
        ss += __shfl_xor(ss, 16);
        ss += __shfl_xor(ss, 32);
        if (lane < 16) {
            atomicAdd(&red[nt * 16 + l15], s);
            atomicAdd(&red[128 + nt * 16 + l15], ss);
        }
    }
    __syncthreads();
    if (t < 128) atomicAdd(&col_sum[t], red[t]);
    else atomicAdd(&col_sumsq[t - 128], red[t]);
}

// ---------------- MFMA GEMM2 (fused BN finalize + bias/relu + graph pool) ----------------
// Phase A: per-block BN scale/shift from col stats; MFMA h = relu(BN(Hpre)) @ Wt.
// Phase B: reuse W-LDS to stage 64-row output windows; segment-reduce per graph -> atomicAdd pool.
__global__ __launch_bounds__(256) void mgemm2_k(
    const float* Hpre, const short* __restrict__ WF,
    const float* __restrict__ col_sum, const float* __restrict__ col_sumsq,
    const float* __restrict__ gw, const float* __restrict__ bw,
    const float* __restrict__ bias,
    const int* __restrict__ batch, const int* __restrict__ gstart,
    float* Hout, unsigned short* __restrict__ Hbf,
    float* __restrict__ outp, int n) {
    constexpr int NC = 16;
    __shared__ __align__(16) char smem[64 * 132 * 4];  // union: Wlds (32 KB) / Llds (33 KB)
    __shared__ float scsh[256];
    short* Wlds = (short*)smem;
    float* Llds = (float*)smem;
    const int t = threadIdx.x;
    const int lane = t & 63, w = t >> 6;
    const int l15 = lane & 15, q = lane >> 4;
    const int row0 = blockIdx.x * 128 + w * 32;

    {
        const int4* s = (const int4*)WF;
        int4* d = (int4*)Wlds;
        for (int i = t; i < 8 * NC * 16; i += 256) d[i] = s[i];
    }
    if (t < 128) {
        float inv_n = 1.0f / (float)n;
        float mean = col_sum[t] * inv_n;
        float var = col_sumsq[t] * inv_n - mean * mean;
        float a = gw[t] * rsqrtf(var + BN_EPS);
        scsh[t] = a;
        scsh[128 + t] = fmaf(-mean, a, bw[t]);
    }
    __syncthreads();

    f32x4 acc[2][8];
#pragma unroll
    for (int rt = 0; rt < 2; ++rt)
#pragma unroll
        for (int nt = 0; nt < 8; ++nt) acc[rt][nt] = (f32x4){0.f, 0.f, 0.f, 0.f};

    const int r0 = row0 + l15, r1 = row0 + 16 + l15;
    const float* p0 = Hpre + (size_t)r0 * 128 + q * 8;
    const float* p1 = Hpre + (size_t)r1 * 128 + q * 8;
    const bool v0 = r0 < n, v1 = r1 < n;
    const bf16x8* WL = (const bf16x8*)Wlds;

#pragma unroll
    for (int b = 0; b < 4; ++b) {
        const int k0 = b * 32 + q * 8;
        float4 sc0 = ld4(&scsh[k0]), sc1 = ld4(&scsh[k0 + 4]);
        float4 sh0 = ld4(&scsh[128 + k0]), sh1 = ld4(&scsh[128 + k0 + 4]);
        bf16x8 a0 = loadA_bn(p0 + b * 32, v0, sc0, sc1, sh0, sh1);
        bf16x8 a1 = loadA_bn(p1 + b * 32, v1, sc0, sc1, sh0, sh1);
#pragma unroll
        for (int nt = 0; nt < 8; ++nt) {
            bf16x8 bf = WL[(nt * NC + b * 4 + q) * 16 + l15];
            acc[0][nt] = __builtin_amdgcn_mfma_f32_16x16x32_bf16(a0, bf, acc[0][nt], 0, 0, 0);
            acc[1][nt] = __builtin_amdgcn_mfma_f32_16x16x32_bf16(a1, bf, acc[1][nt], 0, 0, 0);
        }
    }

    __syncthreads();  // all waves done with Wlds before overwrite

#pragma unroll
    for (int hb = 0; hb < 2; ++hb) {
        const int r0w = blockIdx.x * 128 + hb * 64;
        if ((w >> 1) == hb) {
#pragma unroll
            for (int nt = 0; nt < 8; ++nt) {
                float bcol = bias[nt * 16 + l15];
#pragma unroll
                for (int rt = 0; rt < 2; ++rt) {
                    int rb = row0 + rt * 16 + q * 4;
#pragma unroll
                    for (int i = 0; i < 4; ++i) {
                        int r = rb + i;
                        float o = 0.f;
                        if (r < n) {
                            o = fmaxf(acc[rt][nt][i] + bcol, 0.f);
                            Hout[(size_t)r * 128 + nt * 16 + l15] = o;
                            if (Hbf) Hbf[(size_t)r * 128 + nt * 16 + l15] = (unsigned short)f2bf(o);
                        }
                        Llds[(r - r0w) * 132 + nt * 16 + l15] = o;
                    }
                }
            }
        }
        __syncthreads();
        if (r0w < n) {
            int c = t & 127, half = t >> 7;
            int g = batch[r0w];
            while (g < N_GRAPHS) {
                int segs = max(gstart[g], r0w);
                int sege = min(gstart[g + 1], r0w + 64);
                if (segs >= r0w + 64) break;
                float s = 0.f;
                for (int r = segs + half; r < sege; r += 2) s += Llds[(r - r0w) * 132 + c];
                if (s != 0.f) atomicAdd(&outp[(size_t)g * OUT_STRIDE + c], s);
                if (gstart[g + 1] >= r0w + 64) break;
                ++g;
            }
        }
        __syncthreads();
    }
}

extern "C" void kernel_launch(void* const* d_in, const int* in_sizes, int n_in,
                              void* d_out, int out_size, void* d_ws, size_t ws_size,
                              hipStream_t stream) {
    const float* x = (const float*)d_in[0];
    const int* ei = (const int*)d_in[1];
    const float* ea = (const float*)d_in[2];
    const int* batch = (const int*)d_in[3];
    const int* srcArr = ei;
    const int* dstArr = ei + N_EDGES;

    const float *We[3], *be[3], *W1[3], *gP[3], *bP[3], *W2[3], *b2[3];
    for (int l = 0; l < 3; ++l) {
        int base = 4 + 7 * l;
        We[l] = (const float*)d_in[base + 0];
        be[l] = (const float*)d_in[base + 1];
        W1[l] = (const float*)d_in[base + 2];
        gP[l] = (const float*)d_in[base + 3];
        bP[l] = (const float*)d_in[base + 4];
        W2[l] = (const float*)d_in[base + 5];
        b2[l] = (const float*)d_in[base + 6];
    }

    char* w = (char*)d_ws;
    auto carve = [&](size_t bytes) {
        char* p = w;
        w += (bytes + 255) & ~(size_t)255;
        return p;
    };
    int* deg = (int*)carve((size_t)N_NODES * 4);
    int* rowstart = (int*)carve((size_t)(N_NODES + 1) * 4);
    int* cursor = (int*)carve((size_t)N_NODES * 4);
    int* bsum = (int*)carve((size_t)SCAN_NB * 4);
    int* boff = (int*)carve((size_t)SCAN_NB * 4);
    int* gstart = (int*)carve((size_t)(N_GRAPHS + 1) * 4);
    float4* adj = (float4*)carve((size_t)N_EDGES * 16);
    float* WeT1 = (float*)carve(3 * 128 * 4);
    float* WeT2 = (float*)carve(3 * 128 * 4);
    short* WF1_0 = (short*)carve(8 * 4 * 16 * 8 * 2);    // KP=32
    short* WF1_1 = (short*)carve(8 * 16 * 16 * 8 * 2);   // KP=128
    short* WF1_2 = (short*)carve(8 * 16 * 16 * 8 * 2);
    short* WF2_0 = (short*)carve(8 * 16 * 16 * 8 * 2);
    short* WF2_1 = (short*)carve(8 * 16 * 16 * 8 * 2);
    short* WF2_2 = (short*)carve(8 * 16 * 16 * 8 * 2);
    float* stats = (float*)carve(3 * 256 * 4);           // per-layer col_sum/col_sumsq
    float* x12 = (float*)carve((size_t)N_NODES * 12 * 4);
    float* y0p = (float*)carve((size_t)N_NODES * 32 * 4);
    float* hA = (float*)carve((size_t)N_NODES * 128 * 4);
    float* ybuf = (float*)carve((size_t)N_NODES * 128 * 4);
    unsigned short* hbf = (unsigned short*)carve((size_t)N_NODES * 128 * 2);

    hipMemsetAsync(deg, 0, (size_t)N_NODES * 4, stream);
    hipMemsetAsync(stats, 0, 3 * 256 * 4, stream);
    hipMemsetAsync(d_out, 0, (size_t)out_size * 4, stream);

    prep_k<<<(N_EDGES + 255) / 256, 256, 0, stream>>>(dstArr, deg, x, x12, batch, gstart,
                                                      N_EDGES, N_NODES, N_GRAPHS);
    deg_bsum_k<<<SCAN_NB, 256, 0, stream>>>(deg, bsum, N_NODES);
    bsum_scan_k<<<1, 256, 0, stream>>>(bsum, boff, rowstart, SCAN_NB, N_NODES);
    deg_scan_k<<<SCAN_NB, 256, 0, stream>>>(deg, boff, rowstart, cursor, N_NODES);
    csr_fill_k<<<(N_EDGES + 255) / 256, 256, 0, stream>>>(srcArr, dstArr, ea, cursor, adj, N_EDGES);

    {
        WfragArgs wa;
        wa.W[0] = W1[0]; wa.WF[0] = WF1_0; wa.din[0] = 9;   wa.KP[0] = 32;
        wa.W[1] = W1[1]; wa.WF[1] = WF1_1; wa.din[1] = 128; wa.KP[1] = 128;
        wa.W[2] = W1[2]; wa.WF[2] = WF1_2; wa.din[2] = 128; wa.KP[2] = 128;
        wa.W[3] = W2[0]; wa.WF[3] = WF2_0; wa.din[3] = 128; wa.KP[3] = 128;
        wa.W[4] = W2[1]; wa.WF[4] = WF2_1; wa.din[4] = 128; wa.KP[4] = 128;
        wa.W[5] = W2[2]; wa.WF[5] = WF2_2; wa.din[5] = 128; wa.KP[5] = 128;
        wa.We1 = We[1]; wa.We2 = We[2]; wa.WeT1 = WeT1; wa.WeT2 = WeT2;
        dim3 gw(8, 7);
        wfrag_all_k<<<gw, 256, 0, stream>>>(wa);
    }

    const int gM = (N_NODES + 127) / 128;
    const int gAgg = (N_NODES + 3) / 4;
    float* out_f = (float*)d_out;

    // ---- layer 0 (K=32 padded from din=9) ----
    agg_d9_k<<<(N_NODES + 255) / 256, 256, 0, stream>>>(x12, rowstart, adj, We[0], be[0], y0p, N_NODES);
    mgemm1_k<32><<<gM, 256, 0, stream>>>(y0p, WF1_0, hA, stats, stats + 128, N_NODES);
    mgemm2_k<<<gM, 256, 0, stream>>>(hA, WF2_0, stats, stats + 128, gP[0], bP[0], b2[0],
                                     batch, gstart, hA, hbf, out_f + 0, N_NODES);

    // ---- layer 1 ----
    agg_d128_k<<<gAgg, 256, 0, stream>>>(hA, hbf, rowstart, adj, WeT1, be[1], ybuf, N_NODES);
    mgemm1_k<128><<<gM, 256, 0, stream>>>(ybuf, WF1_1, ybuf, stats + 256, stats + 384, N_NODES);
    mgemm2_k<<<gM, 256, 0, stream>>>(ybuf, WF2_1, stats + 256, stats + 384, gP[1], bP[1], b2[1],
                                     batch, gstart, ybuf, hbf, out_f + 128, N_NODES);

    // ---- layer 2 ----
    agg_d128_k<<<gAgg, 256, 0, stream>>>(ybuf, hbf, rowstart, adj, WeT2, be[2], hA, N_NODES);
    mgemm1_k<128><<<gM, 256, 0, stream>>>(hA, WF1_2, hA, stats + 512, stats + 640, N_NODES);
    mgemm2_k<<<gM, 256, 0, stream>>>(hA, WF2_2, stats + 512, stats + 640, gP[2], bP[2], b2[2],
                                     batch, gstart, hA, nullptr, out_f + 256, N_NODES);
}

// Round 8
// 445.587 us; speedup vs baseline: 1.1566x; 1.0568x over previous
//
#include <hip/hip_runtime.h>

#define N_NODES 50000
#define N_EDGES 800000
#define N_GRAPHS 500
#define DH 128
#define OUT_STRIDE 384
#define BN_EPS 1e-5f
#define SCAN_NB ((N_NODES + 255) / 256)

typedef __attribute__((ext_vector_type(8))) short bf16x8;
typedef __attribute__((ext_vector_type(4))) float f32x4;

__device__ __forceinline__ float4 ld4(const float* p) { return *(const float4*)p; }
__device__ __forceinline__ void st4(float* p, float4 v) { *(float4*)p = v; }

__device__ __forceinline__ short f2bf(float f) {
    union { float f; unsigned u; } v; v.f = f;
    unsigned r = v.u + 0x7FFFu + ((v.u >> 16) & 1u);
    return (short)(r >> 16);
}
__device__ __forceinline__ float bu2f(unsigned short v) {
    union { unsigned u; float f; } x; x.u = ((unsigned)v) << 16; return x.f;
}

// ---------------- fused prep: deg count (edge) + pad_x + graph bounds (node) ----------------
__global__ void prep_k(const int* __restrict__ dst, int* __restrict__ deg,
                       const float* __restrict__ x, float* __restrict__ x12,
                       const int* __restrict__ batch, int* __restrict__ gstart,
                       int E, int n, int G) {
    int i = blockIdx.x * 256 + threadIdx.x;
    if (i < E) atomicAdd(&deg[dst[i]], 1);
    if (i < n) {
        const float* s = x + (size_t)i * 9;
        float* d = x12 + (size_t)i * 12;
        st4(d, make_float4(s[0], s[1], s[2], s[3]));
        st4(d + 4, make_float4(s[4], s[5], s[6], s[7]));
        st4(d + 8, make_float4(s[8], 0.f, 0.f, 0.f));
        int b = batch[i];
        if (i == 0) {
            for (int g = 0; g <= b; ++g) gstart[g] = 0;
        } else {
            int p = batch[i - 1];
            for (int g = p + 1; g <= b; ++g) gstart[g] = i;
        }
        if (i == n - 1) {
            for (int g = b + 1; g <= G; ++g) gstart[g] = n;
        }
    }
}

// hierarchical scan
__global__ void deg_bsum_k(const int* __restrict__ deg, int* __restrict__ bsum, int n) {
    __shared__ int red[256];
    int t = threadIdx.x, i = blockIdx.x * 256 + t;
    red[t] = (i < n) ? deg[i] : 0;
    __syncthreads();
    for (int off = 128; off > 0; off >>= 1) {
        if (t < off) red[t] += red[t + off];
        __syncthreads();
    }
    if (t == 0) bsum[blockIdx.x] = red[0];
}

__global__ void bsum_scan_k(const int* __restrict__ bsum, int* __restrict__ boff,
                            int* __restrict__ rowstart, int nb, int n) {
    __shared__ int s[256];
    int t = threadIdx.x;
    int v = (t < nb) ? bsum[t] : 0;
    s[t] = v;
    __syncthreads();
    for (int off = 1; off < 256; off <<= 1) {
        int u = (t >= off) ? s[t - off] : 0;
        __syncthreads();
        s[t] += u;
        __syncthreads();
    }
    if (t < nb) boff[t] = s[t] - v;
    if (t == 255) rowstart[n] = s[255];
}

__global__ void deg_scan_k(const int* __restrict__ deg, const int* __restrict__ boff,
                           int* __restrict__ rowstart, int* __restrict__ cursor, int n) {
    __shared__ int s[256];
    int t = threadIdx.x, i = blockIdx.x * 256 + t;
    int v = (i < n) ? deg[i] : 0;
    s[t] = v;
    __syncthreads();
    for (int off = 1; off < 256; off <<= 1) {
        int u = (t >= off) ? s[t - off] : 0;
        __syncthreads();
        s[t] += u;
        __syncthreads();
    }
    if (i < n) {
        int r = boff[blockIdx.x] + s[t] - v;
        rowstart[i] = r;
        cursor[i] = r;
    }
}

// interleaved adjacency payload {src(int bits), e0, e1, e2}; one edge/thread
__global__ void csr_fill_k(const int* __restrict__ src, const int* __restrict__ dst,
                           const float* __restrict__ ea, int* __restrict__ cursor,
                           float4* __restrict__ adj, int E) {
    int e = blockIdx.x * 256 + threadIdx.x;
    if (e >= E) return;
    int pos = atomicAdd(&cursor[dst[e]], 1);
    adj[pos] = make_float4(__int_as_float(src[e]), ea[e * 3 + 0], ea[e * 3 + 1], ea[e * 3 + 2]);
}

// ---------------- W -> bf16 MFMA B-frags (+ We transposes in slot y==6) ----------------
struct WfragArgs {
    const float* W[6];
    short* WF[6];
    int din[6];
    int KP[6];
    const float* We1;
    const float* We2;
    float* WeT1;
    float* WeT2;
};

__global__ void wfrag_all_k(WfragArgs a) {
    int which = blockIdx.y;
    int idx = blockIdx.x * 256 + threadIdx.x;
    if (which == 6) {
        if (idx < 384) {
            int r = idx / 3, c = idx - r * 3;
            a.WeT1[c * 128 + r] = a.We1[idx];
        } else if (idx < 768) {
            int j = idx - 384;
            int r = j / 3, c = j - r * 3;
            a.WeT2[c * 128 + r] = a.We2[j];
        }
        return;
    }
    int din = a.din[which], KP = a.KP[which];
    const float* W = a.W[which];
    short* WF = a.WF[which];
    int NC = KP >> 3;
    int total = 8 * NC * 16;
    if (idx >= total) return;
    int n16 = idx & 15;
    int rest = idx >> 4;
    int c = rest % NC;
    int nt = rest / NC;
    int n = nt * 16 + n16;
    union { short s[8]; int4 v; } u;
#pragma unroll
    for (int j = 0; j < 8; ++j) {
        int k = c * 8 + j;
        float val = (k < din) ? W[(size_t)n * din + k] : 0.f;
        u.s[j] = f2bf(val);
    }
    ((int4*)WF)[idx] = u.v;
}

// ---------------- aggregation layer 0: y_bf16[n][32] = pad(x + sum relu(x[src]+Lin(ea))) ----------------
__global__ __launch_bounds__(256) void agg_d9_k(
    const float* __restrict__ x12, const int* __restrict__ rowstart,
    const float4* __restrict__ adj,
    const float* __restrict__ We /*[9][3]*/, const float* __restrict__ be,
    unsigned short* __restrict__ y /*[n][32] bf16*/, int n) {
    int i = blockIdx.x * 256 + threadIdx.x;
    if (i >= n) return;
    float w0[9], w1[9], w2[9], bb[9], acc[9];
#pragma unroll
    for (int j = 0; j < 9; ++j) {
        w0[j] = We[j * 3 + 0];
        w1[j] = We[j * 3 + 1];
        w2[j] = We[j * 3 + 2];
        bb[j] = be[j];
    }
    {
        const float* xr = x12 + (size_t)i * 12;
#pragma unroll
        for (int j = 0; j < 9; ++j) acc[j] = xr[j];
    }
    int k1 = rowstart[i + 1];
    for (int k = rowstart[i]; k < k1; ++k) {
        float4 ed = adj[k];
        int s = __float_as_int(ed.x);
        float e0 = ed.y, e1 = ed.z, e2 = ed.w;
        const float* xr = x12 + (size_t)s * 12;
        float4 r0 = ld4(xr), r1 = ld4(xr + 4), r2 = ld4(xr + 8);
        float xv[9] = {r0.x, r0.y, r0.z, r0.w, r1.x, r1.y, r1.z, r1.w, r2.x};
#pragma unroll
        for (int j = 0; j < 9; ++j) {
            float lin = fmaf(w0[j], e0, fmaf(w1[j], e1, fmaf(w2[j], e2, bb[j])));
            acc[j] += fmaxf(xv[j] + lin, 0.f);
        }
    }
    union { unsigned short s[32]; int4 v[4]; } u;
#pragma unroll
    for (int j = 0; j < 9; ++j) u.s[j] = (unsigned short)f2bf(acc[j]);
#pragma unroll
    for (int j = 9; j < 32; ++j) u.s[j] = 0;
    int4* yp = (int4*)(y + (size_t)i * 32);
#pragma unroll
    for (int j = 0; j < 4; ++j) yp[j] = u.v[j];
}

// ---------------- aggregation d=128: one wave/node, edge-halves, 4-deep ILP; bf16 in/out ----------------
__global__ __launch_bounds__(256) void agg_d128_k(
    const unsigned short* __restrict__ hbf, const int* __restrict__ rowstart,
    const float4* __restrict__ adj,
    const float* __restrict__ WeT /*[3][128]*/, const float* __restrict__ be,
    unsigned short* __restrict__ y /*[n][128] bf16*/, int n) {
    int lane = threadIdx.x & 63;
    int node = blockIdx.x * 4 + (threadIdx.x >> 6);
    if (node >= n) return;
    int l31 = lane & 31, half = lane >> 5;
    int c = l31 * 4;
    float4 w0 = ld4(&WeT[0 * 128 + c]);
    float4 w1 = ld4(&WeT[1 * 128 + c]);
    float4 w2 = ld4(&WeT[2 * 128 + c]);
    float4 b4 = ld4(&be[c]);
    float4 acc = make_float4(0.f, 0.f, 0.f, 0.f);
    const ushort4* hb = (const ushort4*)hbf;
    int k1 = rowstart[node + 1];
    int k = rowstart[node] + half;
    for (; k + 6 < k1; k += 8) {
        float4 e[4] = {adj[k], adj[k + 2], adj[k + 4], adj[k + 6]};
        ushort4 u[4];
#pragma unroll
        for (int j = 0; j < 4; ++j) u[j] = hb[(size_t)__float_as_int(e[j].x) * 32 + l31];
#pragma unroll
        for (int j = 0; j < 4; ++j) {
            acc.x += fmaxf(fmaf(w0.x, e[j].y, fmaf(w1.x, e[j].z, fmaf(w2.x, e[j].w, b4.x))) + bu2f(u[j].x), 0.f);
            acc.y += fmaxf(fmaf(w0.y, e[j].y, fmaf(w1.y, e[j].z, fmaf(w2.y, e[j].w, b4.y))) + bu2f(u[j].y), 0.f);
            acc.z += fmaxf(fmaf(w0.z, e[j].y, fmaf(w1.z, e[j].z, fmaf(w2.z, e[j].w, b4.z))) + bu2f(u[j].z), 0.f);
            acc.w += fmaxf(fmaf(w0.w, e[j].y, fmaf(w1.w, e[j].z, fmaf(w2.w, e[j].w, b4.w))) + bu2f(u[j].w), 0.f);
        }
    }
    for (; k < k1; k += 2) {
        float4 ed = adj[k];
        int s = __float_as_int(ed.x);
        ushort4 ua = hb[(size_t)s * 32 + l31];
        acc.x += fmaxf(fmaf(w0.x, ed.y, fmaf(w1.x, ed.z, fmaf(w2.x, ed.w, b4.x))) + bu2f(ua.x), 0.f);
        acc.y += fmaxf(fmaf(w0.y, ed.y, fmaf(w1.y, ed.z, fmaf(w2.y, ed.w, b4.y))) + bu2f(ua.y), 0.f);
        acc.z += fmaxf(fmaf(w0.z, ed.y, fmaf(w1.z, ed.z, fmaf(w2.z, ed.w, b4.z))) + bu2f(ua.z), 0.f);
        acc.w += fmaxf(fmaf(w0.w, ed.y, fmaf(w1.w, ed.z, fmaf(w2.w, ed.w, b4.w))) + bu2f(ua.w), 0.f);
    }
    acc.x += __shfl_xor(acc.x, 32);
    acc.y += __shfl_xor(acc.y, 32);
    acc.z += __shfl_xor(acc.z, 32);
    acc.w += __shfl_xor(acc.w, 32);
    if (half == 0) {
        ushort4 xv = hb[(size_t)node * 32 + l31];
        ushort4 o;
        o.x = (unsigned short)f2bf(acc.x + bu2f(xv.x));
        o.y = (unsigned short)f2bf(acc.y + bu2f(xv.y));
        o.z = (unsigned short)f2bf(acc.z + bu2f(xv.z));
        o.w = (unsigned short)f2bf(acc.w + bu2f(xv.w));
        ((ushort4*)y)[(size_t)node * 32 + l31] = o;
    }
}

// ---------------- A-fragment helpers ----------------
__device__ __forceinline__ bf16x8 loadAbf(const unsigned short* p, bool v) {
    if (v) return *(const bf16x8*)p;
    bf16x8 z = {0, 0, 0, 0, 0, 0, 0, 0};
    return z;
}

__device__ __forceinline__ bf16x8 loadA_bn(const unsigned short* p, bool v,
                                           float4 sc0, float4 sc1, float4 sh0, float4 sh1) {
    union { short s[8]; bf16x8 v8; } u;
    if (v) {
        union { ushort4 q[2]; unsigned short s[8]; } iv;
        iv.q[0] = *(const ushort4*)p;
        iv.q[1] = *(const ushort4*)(p + 4);
        u.s[0] = f2bf(fmaxf(fmaf(bu2f(iv.s[0]), sc0.x, sh0.x), 0.f));
        u.s[1] = f2bf(fmaxf(fmaf(bu2f(iv.s[1]), sc0.y, sh0.y), 0.f));
        u.s[2] = f2bf(fmaxf(fmaf(bu2f(iv.s[2]), sc0.z, sh0.z), 0.f));
        u.s[3] = f2bf(fmaxf(fmaf(bu2f(iv.s[3]), sc0.w, sh0.w), 0.f));
        u.s[4] = f2bf(fmaxf(fmaf(bu2f(iv.s[4]), sc1.x, sh1.x), 0.f));
        u.s[5] = f2bf(fmaxf(fmaf(bu2f(iv.s[5]), sc1.y, sh1.y), 0.f));
        u.s[6] = f2bf(fmaxf(fmaf(bu2f(iv.s[6]), sc1.z, sh1.z), 0.f));
        u.s[7] = f2bf(fmaxf(fmaf(bu2f(iv.s[7]), sc1.w, sh1.w), 0.f));
    } else {
#pragma unroll
        for (int j = 0; j < 8; ++j) u.s[j] = 0;
    }
    return u.v8;
}

// ---------------- MFMA GEMM1: H(bf16) = Y(bf16) @ Wt, + BN column stats ----------------
template <int KP>
__global__ __launch_bounds__(256) void mgemm1_k(
    const unsigned short* Y /* [n][KP] bf16 */, const short* __restrict__ WF,
    unsigned short* Hout /* [n][128] bf16 */, float* __restrict__ col_sum,
    float* __restrict__ col_sumsq, int n) {
    constexpr int NC = KP / 8;
    constexpr int KB = KP / 32;
    __shared__ short Wlds[8 * NC * 16 * 8];
    __shared__ float red[256];
    const int t = threadIdx.x;
    const int lane = t & 63, w = t >> 6;
    const int l15 = lane & 15, q = lane >> 4;
    const int row0 = blockIdx.x * 128 + w * 32;

    {
        const int4* s = (const int4*)WF;
        int4* d = (int4*)Wlds;
        for (int i = t; i < 8 * NC * 16; i += 256) d[i] = s[i];
    }
    red[t] = 0.f;
    __syncthreads();

    f32x4 acc[2][8];
#pragma unroll
    for (int rt = 0; rt < 2; ++rt)
#pragma unroll
        for (int nt = 0; nt < 8; ++nt) acc[rt][nt] = (f32x4){0.f, 0.f, 0.f, 0.f};

    const int r0 = row0 + l15, r1 = row0 + 16 + l15;
    const unsigned short* p0 = Y + (size_t)r0 * KP + q * 8;
    const unsigned short* p1 = Y + (size_t)r1 * KP + q * 8;
    const bool v0 = r0 < n, v1 = r1 < n;
    const bf16x8* WL = (const bf16x8*)Wlds;

#pragma unroll
    for (int b = 0; b < KB; ++b) {
        bf16x8 a0 = loadAbf(p0 + b * 32, v0);
        bf16x8 a1 = loadAbf(p1 + b * 32, v1);
#pragma unroll
        for (int nt = 0; nt < 8; ++nt) {
            bf16x8 bf = WL[(nt * NC + b * 4 + q) * 16 + l15];
            acc[0][nt] = __builtin_amdgcn_mfma_f32_16x16x32_bf16(a0, bf, acc[0][nt], 0, 0, 0);
            acc[1][nt] = __builtin_amdgcn_mfma_f32_16x16x32_bf16(a1, bf, acc[1][nt], 0, 0, 0);
        }
    }

#pragma unroll
    for (int nt = 0; nt < 8; ++nt) {
        float s = 0.f, ss = 0.f;
#pragma unroll
        for (int rt = 0; rt < 2; ++rt) {
            int rb = row0 + rt * 16 + q * 4;
#pragma unroll
            for (int i = 0; i < 4; ++i) {
                float d = acc[rt][nt][i];
                int r = rb + i;
                if (r < n) Hout[(size_t)r * 128 + nt * 16 + l15] = (unsigned short)f2bf(d);
                s += d;
                ss += d * d;
            }
        }
        s += __shfl_xor(s, 16);
        s += __shfl_xor(s, 32);
        ss += __shfl_xor(ss, 16);
        ss += __shfl_xor(ss, 32);
        if (lane < 16) {
            atomicAdd(&red[nt * 16 + l15], s);
            atomicAdd(&red[128 + nt * 16 + l15], ss);
        }
    }
    __syncthreads();
    if (t < 128) atomicAdd(&col_sum[t], red[t]);
    else atomicAdd(&col_sumsq[t - 128], red[t]);
}

// ---------------- MFMA GEMM2 (fused BN finalize + bias/relu + graph pool); bf16 in/out ----------------
__global__ __launch_bounds__(256) void mgemm2_k(
    const unsigned short* Hpre /* bf16 */, const short* __restrict__ WF,
    const float* __restrict__ col_sum, const float* __restrict__ col_sumsq,
    const float* __restrict__ gw, const float* __restrict__ bw,
    const float* __restrict__ bias,
    const int* __restrict__ batch, const int* __restrict__ gstart,
    unsigned short* __restrict__ Hbf /* bf16 out, may be null */,
    float* __restrict__ outp, int n) {
    constexpr int NC = 16;
    __shared__ __align__(16) char smem[64 * 132 * 4];  // union: Wlds (32 KB) / Llds (33 KB)
    __shared__ float scsh[256];
    short* Wlds = (short*)smem;
    float* Llds = (float*)smem;
    const int t = threadIdx.x;
    const int lane = t & 63, w = t >> 6;
    const int l15 = lane & 15, q = lane >> 4;
    const int row0 = blockIdx.x * 128 + w * 32;

    {
        const int4* s = (const int4*)WF;
        int4* d = (int4*)Wlds;
        for (int i = t; i < 8 * NC * 16; i += 256) d[i] = s[i];
    }
    if (t < 128) {
        float inv_n = 1.0f / (float)n;
        float mean = col_sum[t] * inv_n;
        float var = col_sumsq[t] * inv_n - mean * mean;
        float a = gw[t] * rsqrtf(var + BN_EPS);
        scsh[t] = a;
        scsh[128 + t] = fmaf(-mean, a, bw[t]);
    }
    __syncthreads();

    f32x4 acc[2][8];
#pragma unroll
    for (int rt = 0; rt < 2; ++rt)
#pragma unroll
        for (int nt = 0; nt < 8; ++nt) acc[rt][nt] = (f32x4){0.f, 0.f, 0.f, 0.f};

    const int r0 = row0 + l15, r1 = row0 + 16 + l15;
    const unsigned short* p0 = Hpre + (size_t)r0 * 128 + q * 8;
    const unsigned short* p1 = Hpre + (size_t)r1 * 128 + q * 8;
    const bool v0 = r0 < n, v1 = r1 < n;
    const bf16x8* WL = (const bf16x8*)Wlds;

#pragma unroll
    for (int b = 0; b < 4; ++b) {
        const int k0 = b * 32 + q * 8;
        float4 sc0 = ld4(&scsh[k0]), sc1 = ld4(&scsh[k0 + 4]);
        float4 sh0 = ld4(&scsh[128 + k0]), sh1 = ld4(&scsh[128 + k0 + 4]);
        bf16x8 a0 = loadA_bn(p0 + b * 32, v0, sc0, sc1, sh0, sh1);
        bf16x8 a1 = loadA_bn(p1 + b * 32, v1, sc0, sc1, sh0, sh1);
#pragma unroll
        for (int nt = 0; nt < 8; ++nt) {
            bf16x8 bf = WL[(nt * NC + b * 4 + q) * 16 + l15];
            acc[0][nt] = __builtin_amdgcn_mfma_f32_16x16x32_bf16(a0, bf, acc[0][nt], 0, 0, 0);
            acc[1][nt] = __builtin_amdgcn_mfma_f32_16x16x32_bf16(a1, bf, acc[1][nt], 0, 0, 0);
        }
    }

    __syncthreads();  // all waves done with Wlds before overwrite

#pragma unroll
    for (int hb = 0; hb < 2; ++hb) {
        const int r0w = blockIdx.x * 128 + hb * 64;
        if ((w >> 1) == hb) {
#pragma unroll
            for (int nt = 0; nt < 8; ++nt) {
                float bcol = bias[nt * 16 + l15];
#pragma unroll
                for (int rt = 0; rt < 2; ++rt) {
                    int rb = row0 + rt * 16 + q * 4;
#pragma unroll
                    for (int i = 0; i < 4; ++i) {
                        int r = rb + i;
                        float o = 0.f;
                        if (r < n) {
                            o = fmaxf(acc[rt][nt][i] + bcol, 0.f);
                            if (Hbf) Hbf[(size_t)r * 128 + nt * 16 + l15] = (unsigned short)f2bf(o);
                        }
                        Llds[(r - r0w) * 132 + nt * 16 + l15] = o;
                    }
                }
            }
        }
        __syncthreads();
        if (r0w < n) {
            int c = t & 127, half = t >> 7;
            int g = batch[r0w];
            while (g < N_GRAPHS) {
                int segs = max(gstart[g], r0w);
                int sege = min(gstart[g + 1], r0w + 64);
                if (segs >= r0w + 64) break;
                float s = 0.f;
                for (int r = segs + half; r < sege; r += 2) s += Llds[(r - r0w) * 132 + c];
                if (s != 0.f) atomicAdd(&outp[(size_t)g * OUT_STRIDE + c], s);
                if (gstart[g + 1] >= r0w + 64) break;
                ++g;
            }
        }
        __syncthreads();
    }
}

extern "C" void kernel_launch(void* const* d_in, const int* in_sizes, int n_in,
                              void* d_out, int out_size, void* d_ws, size_t ws_size,
                              hipStream_t stream) {
    const float* x = (const float*)d_in[0];
    const int* ei = (const int*)d_in[1];
    const float* ea = (const float*)d_in[2];
    const int* batch = (const int*)d_in[3];
    const int* srcArr = ei;
    const int* dstArr = ei + N_EDGES;

    const float *We[3], *be[3], *W1[3], *gP[3], *bP[3], *W2[3], *b2[3];
    for (int l = 0; l < 3; ++l) {
        int base = 4 + 7 * l;
        We[l] = (const float*)d_in[base + 0];
        be[l] = (const float*)d_in[base + 1];
        W1[l] = (const float*)d_in[base + 2];
        gP[l] = (const float*)d_in[base + 3];
        bP[l] = (const float*)d_in[base + 4];
        W2[l] = (const float*)d_in[base + 5];
        b2[l] = (const float*)d_in[base + 6];
    }

    char* w = (char*)d_ws;
    auto carve = [&](size_t bytes) {
        char* p = w;
        w += (bytes + 255) & ~(size_t)255;
        return p;
    };
    int* deg = (int*)carve((size_t)N_NODES * 4);
    int* rowstart = (int*)carve((size_t)(N_NODES + 1) * 4);
    int* cursor = (int*)carve((size_t)N_NODES * 4);
    int* bsum = (int*)carve((size_t)SCAN_NB * 4);
    int* boff = (int*)carve((size_t)SCAN_NB * 4);
    int* gstart = (int*)carve((size_t)(N_GRAPHS + 1) * 4);
    float4* adj = (float4*)carve((size_t)N_EDGES * 16);
    float* WeT1 = (float*)carve(3 * 128 * 4);
    float* WeT2 = (float*)carve(3 * 128 * 4);
    short* WF1_0 = (short*)carve(8 * 4 * 16 * 8 * 2);    // KP=32
    short* WF1_1 = (short*)carve(8 * 16 * 16 * 8 * 2);   // KP=128
    short* WF1_2 = (short*)carve(8 * 16 * 16 * 8 * 2);
    short* WF2_0 = (short*)carve(8 * 16 * 16 * 8 * 2);
    short* WF2_1 = (short*)carve(8 * 16 * 16 * 8 * 2);
    short* WF2_2 = (short*)carve(8 * 16 * 16 * 8 * 2);
    float* stats = (float*)carve(3 * 256 * 4);           // per-layer col_sum/col_sumsq
    float* x12 = (float*)carve((size_t)N_NODES * 12 * 4);
    unsigned short* y0p = (unsigned short*)carve((size_t)N_NODES * 32 * 2);
    unsigned short* hbufA = (unsigned short*)carve((size_t)N_NODES * 128 * 2);
    unsigned short* hbufB = (unsigned short*)carve((size_t)N_NODES * 128 * 2);

    hipMemsetAsync(deg, 0, (size_t)N_NODES * 4, stream);
    hipMemsetAsync(stats, 0, 3 * 256 * 4, stream);
    hipMemsetAsync(d_out, 0, (size_t)out_size * 4, stream);

    prep_k<<<(N_EDGES + 255) / 256, 256, 0, stream>>>(dstArr, deg, x, x12, batch, gstart,
                                                      N_EDGES, N_NODES, N_GRAPHS);
    deg_bsum_k<<<SCAN_NB, 256, 0, stream>>>(deg, bsum, N_NODES);
    bsum_scan_k<<<1, 256, 0, stream>>>(bsum, boff, rowstart, SCAN_NB, N_NODES);
    deg_scan_k<<<SCAN_NB, 256, 0, stream>>>(deg, boff, rowstart, cursor, N_NODES);
    csr_fill_k<<<(N_EDGES + 255) / 256, 256, 0, stream>>>(srcArr, dstArr, ea, cursor, adj, N_EDGES);

    {
        WfragArgs wa;
        wa.W[0] = W1[0]; wa.WF[0] = WF1_0; wa.din[0] = 9;   wa.KP[0] = 32;
        wa.W[1] = W1[1]; wa.WF[1] = WF1_1; wa.din[1] = 128; wa.KP[1] = 128;
        wa.W[2] = W1[2]; wa.WF[2] = WF1_2; wa.din[2] = 128; wa.KP[2] = 128;
        wa.W[3] = W2[0]; wa.WF[3] = WF2_0; wa.din[3] = 128; wa.KP[3] = 128;
        wa.W[4] = W2[1]; wa.WF[4] = WF2_1; wa.din[4] = 128; wa.KP[4] = 128;
        wa.W[5] = W2[2]; wa.WF[5] = WF2_2; wa.din[5] = 128; wa.KP[5] = 128;
        wa.We1 = We[1]; wa.We2 = We[2]; wa.WeT1 = WeT1; wa.WeT2 = WeT2;
        dim3 gw(8, 7);
        wfrag_all_k<<<gw, 256, 0, stream>>>(wa);
    }

    const int gM = (N_NODES + 127) / 128;
    const int gAgg = (N_NODES + 3) / 4;
    float* out_f = (float*)d_out;

    // ---- layer 0 (K=32 padded from din=9) ----
    agg_d9_k<<<(N_NODES + 255) / 256, 256, 0, stream>>>(x12, rowstart, adj, We[0], be[0], y0p, N_NODES);
    mgemm1_k<32><<<gM, 256, 0, stream>>>(y0p, WF1_0, hbufB, stats, stats + 128, N_NODES);
    mgemm2_k<<<gM, 256, 0, stream>>>(hbufB, WF2_0, stats, stats + 128, gP[0], bP[0], b2[0],
                                     batch, gstart, hbufA, out_f + 0, N_NODES);

    // ---- layer 1 ----
    agg_d128_k<<<gAgg, 256, 0, stream>>>(hbufA, rowstart, adj, WeT1, be[1], hbufB, N_NODES);
    mgemm1_k<128><<<gM, 256, 0, stream>>>(hbufB, WF1_1, hbufB, stats + 256, stats + 384, N_NODES);
    mgemm2_k<<<gM, 256, 0, stream>>>(hbufB, WF2_1, stats + 256, stats + 384, gP[1], bP[1], b2[1],
                                     batch, gstart, hbufA, out_f + 128, N_NODES);

    // ---- layer 2 ----
    agg_d128_k<<<gAgg, 256, 0, stream>>>(hbufA, rowstart, adj, WeT2, be[2], hbufB, N_NODES);
    mgemm1_k<128><<<gM, 256, 0, stream>>>(hbufB, WF1_2, hbufB, stats + 512, stats + 640, N_NODES);
    mgemm2_k<<<gM, 256, 0, stream>>>(hbufB, WF2_2, stats + 512, stats + 640, gP[2], bP[2], b2[2],
                                     batch, gstart, nullptr, out_f + 256, N_NODES);
}